// Round 1
// baseline (1508.255 us; speedup 1.0000x reference)
//
#include <hip/hip_runtime.h>
#include <hip/hip_bf16.h>

// Grouped GEMM: out[e] = x[e] @ w[e]^T
//   x: [E=16, M=256, K=2048] fp32
//   w: [E=16, N=8192, K=2048] fp32   (K-major == B^T layout, MFMA-friendly)
//   out: [E, M, N] fp32
// Strategy: m97-family 128x128 tile, BK=32, mfma_f32_16x16x32_bf16.
// fp32 -> bf16 conversion fused into the global->LDS staging (registers),
// since HBM traffic of the fp32 weights dominates (1.07 GB of 1.24 GB).

typedef __bf16 bf16_t;
typedef float f32x4 __attribute__((ext_vector_type(4)));
typedef bf16_t bf16x4 __attribute__((ext_vector_type(4)));
typedef bf16_t bf16x8 __attribute__((ext_vector_type(8)));

#define E_ 16
#define M_ 256
#define K_ 2048
#define N_ 8192
#define BM 128
#define BN 128
#define BK 32

__global__ __launch_bounds__(256, 2) void grouped_gemm_bf16mfma(
    const float* __restrict__ X, const float* __restrict__ W,
    float* __restrict__ O)
{
    const int bm = blockIdx.x;   // 0..1   (M tiles)  — fastest: pairs share B-tile in L2
    const int bn = blockIdx.y;   // 0..63  (N tiles)
    const int e  = blockIdx.z;   // 0..15  (expert)

    const float* A = X + (size_t)e * M_ * K_ + (size_t)bm * BM * K_;
    const float* B = W + (size_t)e * N_ * K_ + (size_t)bn * BN * K_;
    float*       C = O + (size_t)e * M_ * N_ + (size_t)bm * BM * N_ + (size_t)bn * BN;

    __shared__ bf16_t As[BM][BK];
    __shared__ bf16_t Bs[BN][BK];

    const int tid  = threadIdx.x;
    const int lane = tid & 63;
    const int wave = tid >> 6;          // 0..3
    const int wm   = (wave >> 1) * 64;  // wave's M offset in tile
    const int wn   = (wave & 1) * 64;   // wave's N offset in tile

    // staging: 128 rows x 32 cols fp32, 256 threads, float4 each, 4 passes
    const int srow = tid >> 3;          // 0..31
    const int scol = (tid & 7) * 4;     // 0..28

    // fragment addressing (16x16x32: lane holds 8 contiguous k)
    const int fr = lane & 15;           // m (A) / n (B) index
    const int fk = (lane >> 4) * 8;     // k offset

    f32x4 acc[4][4];
#pragma unroll
    for (int i = 0; i < 4; ++i)
#pragma unroll
        for (int j = 0; j < 4; ++j)
            acc[i][j] = (f32x4){0.f, 0.f, 0.f, 0.f};

    const float* aptr = A + (size_t)srow * K_ + scol;
    const float* bptr = B + (size_t)srow * K_ + scol;

    for (int k0 = 0; k0 < K_; k0 += BK) {
        // ---- stage global fp32 -> LDS bf16 ----
        f32x4 av[4], bv[4];
#pragma unroll
        for (int p = 0; p < 4; ++p) {
            av[p] = *(const f32x4*)(aptr + (size_t)p * 32 * K_ + k0);
            bv[p] = *(const f32x4*)(bptr + (size_t)p * 32 * K_ + k0);
        }
#pragma unroll
        for (int p = 0; p < 4; ++p) {
            bf16x4 a4, b4;
#pragma unroll
            for (int q = 0; q < 4; ++q) {
                a4[q] = (bf16_t)av[p][q];
                b4[q] = (bf16_t)bv[p][q];
            }
            *(bf16x4*)(&As[srow + p * 32][scol]) = a4;
            *(bf16x4*)(&Bs[srow + p * 32][scol]) = b4;
        }
        __syncthreads();

        // ---- LDS -> frags, MFMA ----
        bf16x8 af[4], bfr[4];
#pragma unroll
        for (int t = 0; t < 4; ++t) {
            af[t]  = *(const bf16x8*)(&As[wm + t * 16 + fr][fk]);
            bfr[t] = *(const bf16x8*)(&Bs[wn + t * 16 + fr][fk]);
        }
#pragma unroll
        for (int i = 0; i < 4; ++i)
#pragma unroll
            for (int j = 0; j < 4; ++j)
                acc[i][j] = __builtin_amdgcn_mfma_f32_16x16x32_bf16(
                    af[i], bfr[j], acc[i][j], 0, 0, 0);
        __syncthreads();
    }

    // ---- epilogue: C/D layout col=lane&15, row=(lane>>4)*4+reg ----
#pragma unroll
    for (int i = 0; i < 4; ++i) {
        const int orow = wm + i * 16 + (lane >> 4) * 4;
#pragma unroll
        for (int j = 0; j < 4; ++j) {
            const int ocol = wn + j * 16 + fr;
#pragma unroll
            for (int r = 0; r < 4; ++r)
                C[(size_t)(orow + r) * N_ + ocol] = acc[i][j][r];
        }
    }
}

extern "C" void kernel_launch(void* const* d_in, const int* in_sizes, int n_in,
                              void* d_out, int out_size, void* d_ws, size_t ws_size,
                              hipStream_t stream) {
    const float* X = (const float*)d_in[0];
    const float* W = (const float*)d_in[1];
    float* O = (float*)d_out;
    dim3 grid(M_ / BM, N_ / BN, E_);   // (2, 64, 16) = 2048 blocks
    dim3 block(256);
    grouped_gemm_bf16mfma<<<grid, block, 0, stream>>>(X, W, O);
}